// Round 3
// baseline (848.951 us; speedup 1.0000x reference)
//
#include <hip/hip_runtime.h>
#include <hip/hip_bf16.h>

// DeepSeekMoE on MI355X. FP32 inputs/output per reference; bf16 MFMA compute.
// Sparse top-2 dispatch (exact vs dense reference: non-topk gates are 0).
// Gate layer-1 uses split-bf16 3-term GEMM so top-2 selection matches fp32 ref.
// R8 (= R7 resubmit after container flake; audited for LDS/launch/deadlock):
// 256x256 8-wave double-buffered GEMM (m201 geometry). Per wave: 128x64
// output, 24 ds_read_b128 per 64 MFMA -> LDS pipe (~85 B/cyc) below parity
// with matrix pipe; ONE barrier+vmcnt drain per 64 MFMA (vs 2 per 16 at
// 128^2). All 8 global_load_lds for tile t+1 issued at the START of tile t's
// compute -> full-tile prefetch distance makes the boundary drain cheap.
// setprio(1) around MFMA clusters (T5). Split gate: BK=32, four co-staged
// 256x32 subtiles (Ah/Al/Bh/Bl), 96 MFMA per barrier. Conflict-free XOR
// swizzles carried from R6 (measured 0 conflicts).

using bf16 = __hip_bfloat16;
typedef __attribute__((ext_vector_type(8))) short short8;
typedef __attribute__((ext_vector_type(4))) float float4v;

#define T_TOK 8192
#define DDIM  1024
#define HDIM  2048
#define NEXP  8

__device__ __forceinline__ float bf2f(short s) {
  unsigned u = ((unsigned)(unsigned short)s) << 16;
  return __builtin_bit_cast(float, u);
}
__device__ __forceinline__ unsigned short f2bf(float f) {
  unsigned u = __builtin_bit_cast(unsigned, f);
  unsigned r = (u + 0x7fffu + ((u >> 16) & 1u)) >> 16;   // RNE
  return (unsigned short)r;
}
__device__ __forceinline__ float gelu_erf_f(float x) {
  return 0.5f * x * (1.0f + erff(x * 0.70710678118654752f));
}
__device__ __forceinline__ float gelu_tanh_f(float x) {
  float t = tanhf(0.7978845608028654f * (x + 0.044715f * x * x * x));
  return 0.5f * x * (1.0f + t);
}
__device__ __forceinline__ void gld_lds16(const bf16* g, bf16* l) {
  __builtin_amdgcn_global_load_lds(
      (const __attribute__((address_space(1))) void*)g,
      (__attribute__((address_space(3))) void*)l, 16, 0, 0);
}

// ---------------- cast x fp32 -> bf16 hi + bf16 residual ----------------
__global__ __launch_bounds__(256) void cast_split_x(
    const float* __restrict__ x, bf16* __restrict__ xh, bf16* __restrict__ xl)
{
  long i = ((long)blockIdx.x * 256 + threadIdx.x) * 4;
  float4v v = *(const float4v*)(x + i);
  short4 h, l;
  short* hp = (short*)&h; short* lp = (short*)&l;
  #pragma unroll
  for (int j = 0; j < 4; ++j) {
    unsigned short hb = f2bf(v[j]);
    hp[j] = (short)hb;
    lp[j] = (short)f2bf(v[j] - bf2f((short)hb));
  }
  *(short4*)((short*)xh + i) = h;
  *(short4*)((short*)xl + i) = l;
}

// ------------- transpose+cast fp32 [R,C] -> bf16 [C,R], batched z -------------
template<bool SPLIT>
__global__ __launch_bounds__(256) void transpose_cast(
    const float* __restrict__ in, bf16* __restrict__ out,
    bf16* __restrict__ outl, int R, int C)
{
  __shared__ float tile[32][33];
  long b = blockIdx.z;
  const float* ip = in + b * (long)R * C;
  short* op = (short*)out + b * (long)R * C;
  short* opl = SPLIT ? (short*)outl + b * (long)R * C : nullptr;
  int c0 = blockIdx.x * 32, r0 = blockIdx.y * 32;
  int tx = threadIdx.x & 31, ty = threadIdx.x >> 5;
  #pragma unroll
  for (int i = ty; i < 32; i += 8)
    tile[i][tx] = ip[(long)(r0 + i) * C + c0 + tx];
  __syncthreads();
  #pragma unroll
  for (int i = ty; i < 32; i += 8) {
    float v = tile[tx][i];
    unsigned short hb = f2bf(v);
    op[(long)(c0 + i) * R + r0 + tx] = (short)hb;
    if (SPLIT)
      opl[(long)(c0 + i) * R + r0 + tx] = (short)f2bf(v - bf2f((short)hb));
  }
}

// ---------------- 256x256 8-wave double-buffered MFMA GEMM ----------------
// C = act(A @ B^T + bias). A [M,Kd] bf16 (ldA), Bt [N,Kd] bf16 (+z*strideB).
// 512 threads = 8 waves (2M x 4N), per-wave output 128x64, acc[8][4].
// LDS: 2 buffers x 64 KB. dense: A 256x64 + B 256x64 per buf (BK=64).
// split: Ah/Al/Bh/Bl 256x32 each per buf (BK=32), 3-term accumulate.
// Schedule per K-tile: [boundary __syncthreads] -> issue 8 gld_lds for t+1
// into buf^1 -> ds_read+MFMA from buf (compiler emits fine-grained lgkmcnt)
// -> boundary (drains vmcnt(0): tile t+1 resident; buffer being overwritten
// was last read one barrier ago). Prefetch distance = full tile.
// Swizzle (16B chunks): dense slot = c ^ (row&7) (row = 128 B = 8 slots);
// split slot = c ^ (row&3) ^ ((row>>2)&1) (row = 64 B = 4 slots). Staged via
// inverse-swizzled per-lane GLOBAL source; LDS dest stays lane-linear.
// GATHER: 0 dense; 1 A-row = perm[i]>>1 (token); 2 A-row = perm[i] (slot).
// ACT: 0 none, 1 gelu(erf), 2 gelu(tanh). WEIGHTED: scale by wslot[slot].
// COMBINE (dense fp32 out, N=DDIM): v += Rout[2*row] + Rout[2*row+1].
template<int ACT, typename OutT, int GATHER, bool WEIGHTED, bool SPLIT, bool COMBINE>
__global__ __launch_bounds__(512, 2) void gemm256(
    const bf16* __restrict__ A, const bf16* __restrict__ Bt,
    const bf16* __restrict__ Al, const bf16* __restrict__ Btl,
    const float* __restrict__ bias, OutT* __restrict__ Cmat,
    int M, int N, int Kd, int ldA,
    long strideB, long strideBias,
    const int* __restrict__ perm, const int* __restrict__ counts,
    const float* __restrict__ wslot, const bf16* __restrict__ RoutC)
{
  __shared__ __align__(16) bf16 lds[65536];   // 2 x 64 KB buffers
  __shared__ int permT[256];

  const int tid = threadIdx.x;
  const int tile_n = blockIdx.x, tile_m = blockIdx.y, z = blockIdx.z;

  int Meff = M;
  if (GATHER) {
    const int* perm_z = perm + (long)z * T_TOK;
    Meff = counts[z];
    if (tile_m * 256 >= Meff) return;   // uniform early-exit (before barriers)
    if (tid < 256) {
      int i = tile_m * 256 + tid;
      permT[tid] = perm_z[i < Meff ? i : (Meff - 1)];
    }
    __syncthreads();
  }
  const float* biasz = bias + (long)z * strideBias;

  const int lane = tid & 63;
  const int wave = tid >> 6;
  const int wr = wave >> 2;          // 0..1 -> row offset wr*128
  const int wc = wave & 3;           // 0..3 -> col offset wc*64
  const int fr = lane & 15;          // m/n index within 16x16 tile
  const int kq = lane >> 4;          // 0..3 -> k-chunk quarter

  float4v acc[8][4];
  #pragma unroll
  for (int i = 0; i < 8; ++i)
    #pragma unroll
    for (int j = 0; j < 4; ++j) acc[i][j] = {0.f, 0.f, 0.f, 0.f};

  // ---- staging pointers: 8 gld issues per K-tile per thread ----
  const bf16* pG[8];
  int dL[8];
  if constexpr (SPLIT) {
    const int r4 = tid >> 2;                       // 0..127
    const int cS = (((tid & 3) ^ (r4 & 3) ^ ((r4 >> 2) & 1))) * 8;
    #pragma unroll
    for (int i = 0; i < 2; ++i) {
      long ra = (long)tile_m * 256 + i * 128 + r4;
      long rb = (long)tile_n * 256 + i * 128 + r4;
      pG[i]     = A   + ra * ldA + cS;  dL[i]     = i * 4096 + tid * 8;          // Ah
      pG[2 + i] = Al  + ra * ldA + cS;  dL[2 + i] = 8192  + i * 4096 + tid * 8;  // Al
      pG[4 + i] = Bt  + rb * Kd  + cS;  dL[4 + i] = 16384 + i * 4096 + tid * 8;  // Bh
      pG[6 + i] = Btl + rb * Kd  + cS;  dL[6 + i] = 24576 + i * 4096 + tid * 8;  // Bl
    }
  } else {
    const int r8 = tid >> 3;                       // 0..63
    const int cD = (((tid & 7) ^ (r8 & 7))) * 8;
    #pragma unroll
    for (int i = 0; i < 4; ++i) {
      int rt = i * 64 + r8;
      long ra;
      if (GATHER) {
        int p = permT[rt];
        ra = (GATHER == 1) ? (long)(p >> 1) : (long)p;
      } else {
        ra = (long)tile_m * 256 + rt;
      }
      pG[i]     = A + ra * ldA + cD;
      dL[i]     = i * 4096 + tid * 8;
      pG[4 + i] = Bt + (long)z * strideB + ((long)tile_n * 256 + rt) * Kd + cD;
      dL[4 + i] = 16384 + i * 4096 + tid * 8;
    }
  }

  const int NT = Kd / (SPLIT ? 32 : 64);
  auto stage = [&](int t, int bb) {
    long k0 = (long)t * (SPLIT ? 32 : 64);
    #pragma unroll
    for (int i = 0; i < 8; ++i)
      gld_lds16(pG[i] + k0, &lds[bb * 32768 + dL[i]]);
  };

  stage(0, 0);
  __syncthreads();                     // tile 0 resident
  int cur = 0;

  for (int t = 0; t < NT; ++t) {
    if (t + 1 < NT) stage(t + 1, cur ^ 1);   // prefetch: full-tile distance
    const int bbase = cur * 32768;

    if constexpr (SPLIT) {
      const int c = kq;                // logical k-chunk 0..3
      short8 bh[4], bl[4];
      #pragma unroll
      for (int ni = 0; ni < 4; ++ni) {
        int row = wc * 64 + ni * 16 + fr;
        int sl = ((c ^ (row & 3) ^ ((row >> 2) & 1))) * 8;
        bh[ni] = *(const short8*)&lds[bbase + 16384 + row * 32 + sl];
        bl[ni] = *(const short8*)&lds[bbase + 24576 + row * 32 + sl];
      }
      #pragma unroll
      for (int mh = 0; mh < 2; ++mh) {
        short8 ah[4], alr[4];
        #pragma unroll
        for (int i = 0; i < 4; ++i) {
          int row = wr * 128 + (mh * 4 + i) * 16 + fr;
          int sl = ((c ^ (row & 3) ^ ((row >> 2) & 1))) * 8;
          ah[i]  = *(const short8*)&lds[bbase + row * 32 + sl];
          alr[i] = *(const short8*)&lds[bbase + 8192 + row * 32 + sl];
        }
        __builtin_amdgcn_s_setprio(1);
        #pragma unroll
        for (int i = 0; i < 4; ++i)
          #pragma unroll
          for (int ni = 0; ni < 4; ++ni)
            acc[mh * 4 + i][ni] = __builtin_amdgcn_mfma_f32_16x16x32_bf16(
                ah[i], bh[ni], acc[mh * 4 + i][ni], 0, 0, 0);
        #pragma unroll
        for (int i = 0; i < 4; ++i)
          #pragma unroll
          for (int ni = 0; ni < 4; ++ni)
            acc[mh * 4 + i][ni] = __builtin_amdgcn_mfma_f32_16x16x32_bf16(
                ah[i], bl[ni], acc[mh * 4 + i][ni], 0, 0, 0);
        #pragma unroll
        for (int i = 0; i < 4; ++i)
          #pragma unroll
          for (int ni = 0; ni < 4; ++ni)
            acc[mh * 4 + i][ni] = __builtin_amdgcn_mfma_f32_16x16x32_bf16(
                alr[i], bh[ni], acc[mh * 4 + i][ni], 0, 0, 0);
        __builtin_amdgcn_s_setprio(0);
      }
    } else {
      #pragma unroll
      for (int kh = 0; kh < 2; ++kh) {
        const int c = kh * 4 + kq;     // logical k-chunk 0..7
        short8 bfr[4];
        #pragma unroll
        for (int ni = 0; ni < 4; ++ni) {
          int row = wc * 64 + ni * 16 + fr;
          bfr[ni] = *(const short8*)&lds[bbase + 16384 + row * 64
                                         + ((c ^ (row & 7)) * 8)];
        }
        #pragma unroll
        for (int mh = 0; mh < 2; ++mh) {
          short8 af[4];
          #pragma unroll
          for (int i = 0; i < 4; ++i) {
            int row = wr * 128 + (mh * 4 + i) * 16 + fr;
            af[i] = *(const short8*)&lds[bbase + row * 64
                                         + ((c ^ (row & 7)) * 8)];
          }
          __builtin_amdgcn_s_setprio(1);
          #pragma unroll
          for (int i = 0; i < 4; ++i)
            #pragma unroll
            for (int ni = 0; ni < 4; ++ni)
              acc[mh * 4 + i][ni] = __builtin_amdgcn_mfma_f32_16x16x32_bf16(
                  af[i], bfr[ni], acc[mh * 4 + i][ni], 0, 0, 0);
          __builtin_amdgcn_s_setprio(0);
        }
      }
    }
    __syncthreads();   // drains t+1's gld (issued a full tile ago) + readers
    cur ^= 1;
  }

  // --- epilogue: C/D layout col(n)=lane&15, row(m)=(lane>>4)*4+reg ---
  const int rq = kq * 4;
  #pragma unroll
  for (int mi = 0; mi < 8; ++mi) {
    #pragma unroll
    for (int r = 0; r < 4; ++r) {
      int irow = wr * 128 + mi * 16 + rq + r;
      int gi = tile_m * 256 + irow;
      long crow;
      bool valid = true;
      float w = 1.f;
      if (GATHER) {
        valid = gi < Meff;
        int p = permT[irow];
        crow = p;
        if (WEIGHTED) w = valid ? wslot[p] : 0.f;
      } else {
        crow = gi;
      }
      if (valid) {
        #pragma unroll
        for (int ni = 0; ni < 4; ++ni) {
          int gcol = tile_n * 256 + wc * 64 + ni * 16 + fr;
          float v = acc[mi][ni][r] + biasz[gcol];
          if (ACT == 1) v = gelu_erf_f(v);
          else if (ACT == 2) v = gelu_tanh_f(v);
          if (WEIGHTED) v *= w;
          if (COMBINE) {
            const short* rs = (const short*)RoutC;
            v += bf2f(rs[(2 * crow) * DDIM + gcol])
               + bf2f(rs[(2 * crow + 1) * DDIM + gcol]);
          }
          long cidx = crow * (long)N + gcol;
          if (sizeof(OutT) == 4) ((float*)Cmat)[cidx] = v;
          else ((unsigned short*)Cmat)[cidx] = f2bf(v);
        }
      }
    }
  }
}

// -------- logits: one wave per token; fp32 reduce; top-2 + softmax --------
__global__ __launch_bounds__(256) void logits_kernel(
    const float* __restrict__ G1, const float* __restrict__ gw2,
    const float* __restrict__ gb2, int* __restrict__ tidx,
    float* __restrict__ wslot)
{
  int wv = threadIdx.x >> 6, lane = threadIdx.x & 63;
  int t = blockIdx.x * 4 + wv;
  const float* grow = G1 + (long)t * HDIM;
  float acc[NEXP];
  #pragma unroll
  for (int e = 0; e < NEXP; ++e) acc[e] = 0.f;
  for (int j = 0; j < HDIM / 64; ++j) {
    int h = j * 64 + lane;
    float g = grow[h];                      // coalesced across the wave
    float4v w0 = *(const float4v*)&gw2[h * NEXP];
    float4v w1 = *(const float4v*)&gw2[h * NEXP + 4];
    #pragma unroll
    for (int e = 0; e < 4; ++e) {
      acc[e]     += g * w0[e];
      acc[e + 4] += g * w1[e];
    }
  }
  #pragma unroll
  for (int off = 32; off >= 1; off >>= 1)
    #pragma unroll
    for (int e = 0; e < NEXP; ++e) acc[e] += __shfl_xor(acc[e], off);

  if (lane == 0) {
    float lg[NEXP];
    #pragma unroll
    for (int e = 0; e < NEXP; ++e) lg[e] = acc[e] + gb2[e];
    int i1 = 0;
    for (int e = 1; e < NEXP; ++e) if (lg[e] > lg[i1]) i1 = e;   // ties -> lowest
    int i2 = (i1 == 0) ? 1 : 0;
    for (int e = 0; e < NEXP; ++e) {
      if (e == i1) continue;
      if (lg[e] > lg[i2]) i2 = e;
    }
    float m = lg[i1], s = 0.f;
    #pragma unroll
    for (int e = 0; e < NEXP; ++e) s += expf(lg[e] - m);
    float inv = 1.f / s;
    tidx[2 * t]     = i1;
    tidx[2 * t + 1] = i2;
    wslot[2 * t]     = expf(lg[i1] - m) * inv;
    wslot[2 * t + 1] = expf(lg[i2] - m) * inv;
  }
}

// -------- dispatch: ballot-aggregated per-expert slot lists --------
__global__ __launch_bounds__(256) void dispatch_kernel(
    const int* __restrict__ tidx, int* __restrict__ counts,
    int* __restrict__ perm)
{
  int t = blockIdx.x * 256 + threadIdx.x;
  int lane = threadIdx.x & 63;
  #pragma unroll
  for (int k = 0; k < 2; ++k) {
    int e = tidx[2 * t + k];
    #pragma unroll
    for (int ex = 0; ex < NEXP; ++ex) {
      unsigned long long m = __ballot(e == ex);
      if (m) {                                 // wave-uniform
        int leader = __ffsll((unsigned long long)m) - 1;
        int base = 0;
        if (lane == leader) base = atomicAdd(&counts[ex], __popcll(m));
        base = __shfl(base, leader);
        if (e == ex) {
          int pos = base + __popcll(m & ((1ULL << lane) - 1ULL));
          perm[ex * T_TOK + pos] = 2 * t + k;
        }
      }
    }
  }
}

extern "C" void kernel_launch(void* const* d_in, const int* in_sizes, int n_in,
                              void* d_out, int out_size, void* d_ws, size_t ws_size,
                              hipStream_t stream)
{
  const float* x   = (const float*)d_in[0];
  // d_in[1] = task_ids (unused by reference)
  const float* gw1 = (const float*)d_in[2];
  const float* gb1 = (const float*)d_in[3];
  const float* gw2 = (const float*)d_in[4];
  const float* gb2 = (const float*)d_in[5];
  const float* We1 = (const float*)d_in[6];
  const float* be1 = (const float*)d_in[7];
  const float* We2 = (const float*)d_in[8];
  const float* be2 = (const float*)d_in[9];
  const float* Ws1 = (const float*)d_in[10];
  const float* bs1 = (const float*)d_in[11];
  const float* Ws2 = (const float*)d_in[12];
  const float* bs2 = (const float*)d_in[13];
  float* out = (float*)d_out;

  // ---- workspace layout (176.3 MiB, lifetime-overlapped) ----
  char* ws = (char*)d_ws;
  bf16*  xb     = (bf16*)(ws + 0);              // 16 MiB [T,D] hi
  bf16*  We1t   = (bf16*)(ws + 16777216);       // 32 MiB [E,H,D]
  bf16*  Rout   = (bf16*)(ws + 16777216);       // 32 MiB [2T,D] (reuses We1t)
  bf16*  We2t   = (bf16*)(ws + 50331648);       // 32 MiB [E,D,H]
  bf16*  Ws1t   = (bf16*)(ws + 83886080);       //  4 MiB [H,D]
  bf16*  Ws2t   = (bf16*)(ws + 88080384);       //  4 MiB [D,H]
  int*   counts = (int*)(ws + 92274688);        // 1 KiB pad
  float* wslot  = (float*)(ws + 92275712);      // 64 KiB [2T]
  int*   perm   = (int*)(ws + 92341248);        // 256 KiB [E,T]
  bf16*  xl     = (bf16*)(ws + 92603392);       // 16 MiB [T,D] lo
  bf16*  gw1h   = (bf16*)(ws + 109380608);      //  4 MiB [H,D] hi
  bf16*  gw1l   = (bf16*)(ws + 113574912);      //  4 MiB [H,D] lo
  int*   tidx   = (int*)(ws + 113574912);       // 64 KiB [2T] (reuses gw1l after gate GEMM)
  float* G1     = (float*)(ws + 117769216);     // 64 MiB [T,H] fp32
  bf16*  Hrt    = (bf16*)(ws + 117769216);      // 64 MiB [2T,H] (reuses G1)
  bf16*  S1     = (bf16*)(ws + 117769216);      // 32 MiB [T,H]  (reuses Hrt)

  hipMemsetAsync(counts, 0, NEXP * sizeof(int), stream);

  dim3 blk(256), blk2(512);
  // x cast (hi+lo)
  cast_split_x<<<dim3((T_TOK * DDIM) / 1024), blk, 0, stream>>>(x, xb, xl);
  // weight cast+transpose ([K,N] fp32 -> [N,K] bf16)
  transpose_cast<true ><<<dim3(HDIM/32, DDIM/32, 1), blk, 0, stream>>>(gw1, gw1h, gw1l, DDIM, HDIM);
  transpose_cast<false><<<dim3(HDIM/32, DDIM/32, 1), blk, 0, stream>>>(Ws1, Ws1t, nullptr, DDIM, HDIM);
  transpose_cast<false><<<dim3(DDIM/32, HDIM/32, 1), blk, 0, stream>>>(Ws2, Ws2t, nullptr, HDIM, DDIM);
  transpose_cast<false><<<dim3(HDIM/32, DDIM/32, NEXP), blk, 0, stream>>>(We1, We1t, nullptr, DDIM, HDIM);
  transpose_cast<false><<<dim3(DDIM/32, HDIM/32, NEXP), blk, 0, stream>>>(We2, We2t, nullptr, HDIM, DDIM);

  // gate GEMM1 (split-bf16, fused 3-term, fp32 out): G1 = gelu_erf(x @ gw1 + gb1)
  gemm256<1, float, 0, false, true, false><<<dim3(HDIM/256, T_TOK/256, 1), blk2, 0, stream>>>(
      xb, gw1h, xl, gw1l, gb1, G1, T_TOK, HDIM, DDIM, DDIM, 0, 0,
      nullptr, nullptr, nullptr, nullptr);
  // gating: logits + top-2 + softmax, then ballot-aggregated dispatch
  logits_kernel<<<dim3(T_TOK / 4), blk, 0, stream>>>(G1, gw2, gb2, tidx, wslot);
  dispatch_kernel<<<dim3(T_TOK / 256), blk, 0, stream>>>(tidx, counts, perm);
  // routed experts (gathered) -- before shared so shared GEMM2 can fuse combine
  gemm256<2, bf16, 1, false, false, false><<<dim3(HDIM/256, T_TOK/256, NEXP), blk2, 0, stream>>>(
      xb, We1t, nullptr, nullptr, be1, Hrt, T_TOK, HDIM, DDIM, DDIM,
      (long)HDIM * DDIM, HDIM, perm, counts, nullptr, nullptr);
  gemm256<0, bf16, 2, true, false, false><<<dim3(DDIM/256, T_TOK/256, NEXP), blk2, 0, stream>>>(
      Hrt, We2t, nullptr, nullptr, be2, Rout, T_TOK, DDIM, HDIM, HDIM,
      (long)DDIM * HDIM, DDIM, perm, counts, wslot, nullptr);
  // shared expert; GEMM2 epilogue fuses the routed combine -> final out
  gemm256<2, bf16, 0, false, false, false><<<dim3(HDIM/256, T_TOK/256, 1), blk2, 0, stream>>>(
      xb, Ws1t, nullptr, nullptr, bs1, S1, T_TOK, HDIM, DDIM, DDIM, 0, 0,
      nullptr, nullptr, nullptr, nullptr);
  gemm256<0, float, 0, false, false, true><<<dim3(DDIM/256, T_TOK/256, 1), blk2, 0, stream>>>(
      S1, Ws2t, nullptr, nullptr, bs2, out, T_TOK, DDIM, HDIM, HDIM, 0, 0,
      nullptr, nullptr, nullptr, Rout);
}